// Round 1
// baseline (225.946 us; speedup 1.0000x reference)
//
#include <hip/hip_runtime.h>

#define N_NODES 100000
#define N_EDGES 1600000
#define MSG 16
#define HID 16
#define NT 8
#define NC 32

// ---------------------------------------------------------------------------
// Phase 1: Y[n][t][j] = sum_k edge_table[t][j*HID+k] * feat[n][k]
// One thread per node. edge_table accesses are wave-uniform -> scalar loads.
// ---------------------------------------------------------------------------
__global__ __launch_bounds__(256) void ggnn_phase1(
    const float* __restrict__ feat,
    const float* __restrict__ edge_table,
    float* __restrict__ Y) {
    int n = blockIdx.x * 256 + threadIdx.x;
    if (n >= N_NODES) return;

    float h[HID];
    const float4* f4 = reinterpret_cast<const float4*>(feat + (size_t)n * HID);
    #pragma unroll
    for (int q = 0; q < HID / 4; ++q) {
        float4 v = f4[q];
        h[q * 4 + 0] = v.x; h[q * 4 + 1] = v.y;
        h[q * 4 + 2] = v.z; h[q * 4 + 3] = v.w;
    }

    float4* yrow = reinterpret_cast<float4*>(Y + (size_t)n * (NT * MSG));
    for (int t = 0; t < NT; ++t) {
        const float* At = edge_table + t * (MSG * HID);
        #pragma unroll
        for (int j4 = 0; j4 < MSG / 4; ++j4) {
            float4 o;
            float* op = &o.x;
            #pragma unroll
            for (int jj = 0; jj < 4; ++jj) {
                const float* a = At + (j4 * 4 + jj) * HID;
                float acc = 0.f;
                #pragma unroll
                for (int k = 0; k < HID; ++k) acc += a[k] * h[k];
                op[jj] = acc;
            }
            yrow[t * (MSG / 4) + j4] = o;
        }
    }
}

// ---------------------------------------------------------------------------
// Phase 2: m[dst[e]][j] += Y[src[e]][etype[e]][j]
// 16 lanes per edge: coalesced 64B gather, 16 consecutive f32 atomics.
// ---------------------------------------------------------------------------
__global__ __launch_bounds__(256) void ggnn_phase2(
    const int* __restrict__ src,
    const int* __restrict__ dst,
    const int* __restrict__ etype,
    const float* __restrict__ Y,
    float* __restrict__ m) {
    long long tid = (long long)blockIdx.x * 256 + threadIdx.x;
    int e = (int)(tid >> 4);
    int j = (int)(tid & 15);
    if (e >= N_EDGES) return;
    int s = src[e];
    int d = dst[e];
    int t = etype[e];
    float v = Y[(size_t)s * (NT * MSG) + t * MSG + j];
    atomicAdd(m + (size_t)d * MSG + j, v);
}

// ---------------------------------------------------------------------------
// Phase 3: GRU cell + output projection. One thread per node; weights are
// wave-uniform -> scalar loads through constant cache.
// ---------------------------------------------------------------------------
__device__ __forceinline__ float fast_sigmoid(float x) {
    return 1.f / (1.f + __expf(-x));
}
__device__ __forceinline__ float fast_tanh(float x) {
    return 2.f / (1.f + __expf(-2.f * x)) - 1.f;
}

__global__ __launch_bounds__(256) void ggnn_phase3(
    const float* __restrict__ feat,
    const float* __restrict__ m,
    const float* __restrict__ W_ih,
    const float* __restrict__ W_hh,
    const float* __restrict__ b_ih,
    const float* __restrict__ b_hh,
    const float* __restrict__ W_out,
    const float* __restrict__ b_out,
    float* __restrict__ out) {
    int n = blockIdx.x * 256 + threadIdx.x;
    if (n >= N_NODES) return;

    float mv[MSG], h[HID];
    {
        const float4* m4 = reinterpret_cast<const float4*>(m + (size_t)n * MSG);
        const float4* f4 = reinterpret_cast<const float4*>(feat + (size_t)n * HID);
        #pragma unroll
        for (int q = 0; q < 4; ++q) {
            float4 a = m4[q];
            mv[q * 4 + 0] = a.x; mv[q * 4 + 1] = a.y;
            mv[q * 4 + 2] = a.z; mv[q * 4 + 3] = a.w;
            float4 b = f4[q];
            h[q * 4 + 0] = b.x; h[q * 4 + 1] = b.y;
            h[q * 4 + 2] = b.z; h[q * 4 + 3] = b.w;
        }
    }

    // r and z gates only ever need gi+gh; n gate needs them separately.
    float srz[2 * HID];
    for (int g = 0; g < 2 * HID; ++g) {
        float ai = 0.f, ah = 0.f;
        const float* wi = W_ih + g * MSG;
        const float* wh = W_hh + g * HID;
        #pragma unroll
        for (int k = 0; k < HID; ++k) {
            ai += wi[k] * mv[k];
            ah += wh[k] * h[k];
        }
        srz[g] = ai + ah + b_ih[g] + b_hh[g];
    }
    float i_n[HID], h_n[HID];
    #pragma unroll
    for (int j = 0; j < HID; ++j) {
        int g = 2 * HID + j;
        float ai = b_ih[g], ah = b_hh[g];
        const float* wi = W_ih + g * MSG;
        const float* wh = W_hh + g * HID;
        #pragma unroll
        for (int k = 0; k < HID; ++k) {
            ai += wi[k] * mv[k];
            ah += wh[k] * h[k];
        }
        i_n[j] = ai;
        h_n[j] = ah;
    }

    float hn[HID];
    #pragma unroll
    for (int j = 0; j < HID; ++j) {
        float r = fast_sigmoid(srz[j]);
        float z = fast_sigmoid(srz[HID + j]);
        float nn = fast_tanh(i_n[j] + r * h_n[j]);
        hn[j] = (1.f - z) * nn + z * h[j];
    }

    float4* op = reinterpret_cast<float4*>(out + (size_t)n * NC);
    #pragma unroll
    for (int c4 = 0; c4 < NC / 4; ++c4) {
        float4 o;
        float* oo = &o.x;
        #pragma unroll
        for (int cc = 0; cc < 4; ++cc) {
            int c = c4 * 4 + cc;
            float acc = b_out[c];
            const float* wo = W_out + c * HID;
            #pragma unroll
            for (int k = 0; k < HID; ++k) acc += wo[k] * hn[k];
            oo[cc] = acc;
        }
        op[c4] = o;
    }
}

extern "C" void kernel_launch(void* const* d_in, const int* in_sizes, int n_in,
                              void* d_out, int out_size, void* d_ws, size_t ws_size,
                              hipStream_t stream) {
    const float* feat       = (const float*)d_in[0];
    const int*   src        = (const int*)d_in[1];
    const int*   dst        = (const int*)d_in[2];
    const int*   etype      = (const int*)d_in[3];
    const float* edge_table = (const float*)d_in[4];
    const float* W_ih       = (const float*)d_in[5];
    const float* W_hh       = (const float*)d_in[6];
    const float* b_ih       = (const float*)d_in[7];
    const float* b_hh       = (const float*)d_in[8];
    const float* W_out      = (const float*)d_in[9];
    const float* b_out      = (const float*)d_in[10];
    float* out = (float*)d_out;

    // workspace: m [N, MSG] f32, then Y [N, NT, MSG] f32  (total 57.6 MB)
    float* m = (float*)d_ws;
    float* Y = m + (size_t)N_NODES * MSG;

    hipMemsetAsync(m, 0, (size_t)N_NODES * MSG * sizeof(float), stream);

    int blocks1 = (N_NODES + 255) / 256;
    ggnn_phase1<<<blocks1, 256, 0, stream>>>(feat, edge_table, Y);

    long long p2_threads = (long long)N_EDGES * 16;
    int blocks2 = (int)((p2_threads + 255) / 256);
    ggnn_phase2<<<blocks2, 256, 0, stream>>>(src, dst, etype, Y, m);

    ggnn_phase3<<<blocks1, 256, 0, stream>>>(feat, m, W_ih, W_hh, b_ih, b_hh,
                                             W_out, b_out, out);
}